// Round 2
// baseline (778.357 us; speedup 1.0000x reference)
//
#include <hip/hip_runtime.h>

#define NSEG 256
#define D 128
#define COL4 32                      // float4 per row
#define SLOTS 8                      // 32-thread slots per 256-thread block
#define ROWS_PER_SLOT 32
#define ROWS_PER_BLOCK (SLOTS * ROWS_PER_SLOT)   // 256 rows per block

// ws layout: float sums[NSEG][D] (128 KB) then float counts[NSEG]
__global__ void zero_ws_kernel(float* ws) {
    int i = blockIdx.x * blockDim.x + threadIdx.x;
    if (i < NSEG * D + NSEG) ws[i] = 0.f;
}

__global__ __launch_bounds__(256) void partial_kernel(const float4* __restrict__ inp,
                                                      const int* __restrict__ seg,
                                                      float* __restrict__ sums,
                                                      float* __restrict__ counts,
                                                      int n) {
    const int col  = threadIdx.x & 31;   // which float4 of the row
    const int slot = threadIdx.x >> 5;
    const int r0 = blockIdx.x * ROWS_PER_BLOCK + slot * ROWS_PER_SLOT;
    if (r0 >= n) return;
    const int r1 = (r0 + ROWS_PER_SLOT < n) ? r0 + ROWS_PER_SLOT : n;

    int cur = seg[r0];
    float4 acc = make_float4(0.f, 0.f, 0.f, 0.f);
    int runlen = 0;

    #pragma unroll 4
    for (int r = r0; r < r1; ++r) {
        int s = seg[r];                              // broadcast within slot (L1)
        float4 v = inp[(size_t)r * COL4 + col];      // coalesced 16B/lane
        if (s != cur) {                              // rare: ~0.8% of slots ever take this
            float* dst = sums + (size_t)cur * D + col * 4;
            atomicAdd(dst + 0, acc.x);
            atomicAdd(dst + 1, acc.y);
            atomicAdd(dst + 2, acc.z);
            atomicAdd(dst + 3, acc.w);
            if (col == 0) atomicAdd(counts + cur, (float)runlen);
            cur = s;
            acc = make_float4(0.f, 0.f, 0.f, 0.f);
            runlen = 0;
        }
        acc.x += v.x; acc.y += v.y; acc.z += v.z; acc.w += v.w;
        ++runlen;
    }

    float* dst = sums + (size_t)cur * D + col * 4;
    atomicAdd(dst + 0, acc.x);
    atomicAdd(dst + 1, acc.y);
    atomicAdd(dst + 2, acc.z);
    atomicAdd(dst + 3, acc.w);
    if (col == 0) atomicAdd(counts + cur, (float)runlen);
}

__global__ void finalize_kernel(const float* __restrict__ sums,
                                const float* __restrict__ counts,
                                float* __restrict__ out) {
    int i = blockIdx.x * blockDim.x + threadIdx.x;   // over NSEG*D
    if (i < NSEG * D) {
        int s = i >> 7;                              // i / D
        float c = counts[s];
        c = (c > 1.f) ? c : 1.f;
        out[i] = sums[i] / c;
    }
}

extern "C" void kernel_launch(void* const* d_in, const int* in_sizes, int n_in,
                              void* d_out, int out_size, void* d_ws, size_t ws_size,
                              hipStream_t stream) {
    const float* inp = (const float*)d_in[0];
    const int* seg   = (const int*)d_in[1];
    float* out       = (float*)d_out;
    const int n = in_sizes[1];                       // 1048576 rows

    float* sums   = (float*)d_ws;                    // NSEG*D floats
    float* counts = sums + NSEG * D;                 // NSEG floats

    zero_ws_kernel<<<(NSEG * D + NSEG + 255) / 256, 256, 0, stream>>>(sums);

    const int nblocks = (n + ROWS_PER_BLOCK - 1) / ROWS_PER_BLOCK;   // 4096
    partial_kernel<<<nblocks, 256, 0, stream>>>((const float4*)inp, seg, sums, counts, n);

    finalize_kernel<<<(NSEG * D + 255) / 256, 256, 0, stream>>>(sums, counts, out);
}